// Round 3
// baseline (87.457 us; speedup 1.0000x reference)
//
#include <hip/hip_runtime.h>
#include <math.h>

// Problem constants (fixed by the reference).
#define BB 128
#define II 256
#define OO 4096
#define DECAY 0.95f

constexpr int TB  = 16;        // bi rows per block (4 per wave, wave-uniform)
constexpr int TO  = 64;        // o cols per block (one per lane)
constexpr int IC  = 64;        // i-chunk staged in LDS
constexpr int PAD = 4;         // +4 floats row pad -> b128 reads conflict-free
constexpr int LDW = IC + PAD;  // 68

// CALIBRATION ROUND: run the (idempotent) max-reduction core loop REPS times.
// Output is bit-identical for any REPS >= 1; dur delta vs REPS=1 measures the
// core-loop time directly, discriminating "kernel-bound" vs "harness-fill-
// bound" dur_us.
constexpr int REPS = 2;

__global__ __launch_bounds__(256) void stimulus_linf_kernel(
    const float* __restrict__ x,     // (B, I)
    const float* __restrict__ stim,  // (O, I)
    const float* __restrict__ a,     // (O,)
    const float* __restrict__ b,     // (O,)
    const float* __restrict__ state, // (B, O)
    float* __restrict__ out)         // (B, O)
{
    __shared__ float s_stim[TO][LDW];   // only stim lives in LDS (17.4 KB)

    const int tid  = threadIdx.x;
    const int lane = tid & 63;
    const int wave = tid >> 6;

    const int o_tile  = blockIdx.x & 63;
    const int bi_tile = blockIdx.x >> 6;
    const int o_base  = o_tile * TO;
    const int bi_base = bi_tile * TB;

    // Wave-uniform x-row base, forced scalar -> SMEM-pipe loads for x.
    const int wrow = __builtin_amdgcn_readfirstlane(bi_base + wave * 4);

    float d[4] = {0.f, 0.f, 0.f, 0.f};  // |.| >= 0 so 0-init is exact

    #pragma unroll 1
    for (int rep = 0; rep < REPS; ++rep) {
        #pragma unroll 1
        for (int ic = 0; ic < II; ic += IC) {
            // ---- stage stim tile: TO x IC = 4096 floats = 1024 float4 ----
            #pragma unroll
            for (int k = 0; k < 4; ++k) {
                const int idx = tid + k * 256;
                const int row = idx >> 4;   // 16 float4 per row
                const int c4  = idx & 15;
                const float4 v = *reinterpret_cast<const float4*>(
                    &stim[(o_base + row) * II + ic + c4 * 4]);
                *reinterpret_cast<float4*>(&s_stim[row][c4 * 4]) = v;
            }
            __syncthreads();

            // Scalar (uniform) x-row pointers for this chunk.
            const float4* xr0 = reinterpret_cast<const float4*>(x + (wrow + 0) * II + ic);
            const float4* xr1 = reinterpret_cast<const float4*>(x + (wrow + 1) * II + ic);
            const float4* xr2 = reinterpret_cast<const float4*>(x + (wrow + 2) * II + ic);
            const float4* xr3 = reinterpret_cast<const float4*>(x + (wrow + 3) * II + ic);

            // ---- compute: lane = one o; wave owns 4 bi rows (scalar x) ----
            #pragma unroll
            for (int i4 = 0; i4 < IC / 4; ++i4) {
                const float4 s4 =
                    *reinterpret_cast<const float4*>(&s_stim[lane][i4 * 4]);
                const float4 xv0 = xr0[i4];
                const float4 xv1 = xr1[i4];
                const float4 xv2 = xr2[i4];
                const float4 xv3 = xr3[i4];
                d[0] = fmaxf(fmaxf(d[0], fabsf(xv0.x - s4.x)), fabsf(xv0.y - s4.y));
                d[0] = fmaxf(fmaxf(d[0], fabsf(xv0.z - s4.z)), fabsf(xv0.w - s4.w));
                d[1] = fmaxf(fmaxf(d[1], fabsf(xv1.x - s4.x)), fabsf(xv1.y - s4.y));
                d[1] = fmaxf(fmaxf(d[1], fabsf(xv1.z - s4.z)), fabsf(xv1.w - s4.w));
                d[2] = fmaxf(fmaxf(d[2], fabsf(xv2.x - s4.x)), fabsf(xv2.y - s4.y));
                d[2] = fmaxf(fmaxf(d[2], fabsf(xv2.z - s4.z)), fabsf(xv2.w - s4.w));
                d[3] = fmaxf(fmaxf(d[3], fabsf(xv3.x - s4.x)), fabsf(xv3.y - s4.y));
                d[3] = fmaxf(fmaxf(d[3], fabsf(xv3.z - s4.z)), fabsf(xv3.w - s4.w));
            }
            __syncthreads();  // protect LDS before next chunk's staging
        }
    }

    // ---- epilogue: sigmoid((a - d) * b); state*DECAY + value ----
    const int o  = o_base + lane;
    const float av = a[o];
    const float bv = b[o];
    #pragma unroll
    for (int r = 0; r < 4; ++r) {
        const int bi = bi_base + wave * 4 + r;
        const float z   = (av - d[r]) * bv;
        const float val = 1.f / (1.f + __expf(-z));
        out[bi * OO + o] = state[bi * OO + o] * DECAY + val;
    }
}

extern "C" void kernel_launch(void* const* d_in, const int* in_sizes, int n_in,
                              void* d_out, int out_size, void* d_ws, size_t ws_size,
                              hipStream_t stream) {
    const float* x     = (const float*)d_in[0];
    const float* stim  = (const float*)d_in[1];
    const float* a     = (const float*)d_in[2];
    const float* b     = (const float*)d_in[3];
    const float* state = (const float*)d_in[4];
    float* out = (float*)d_out;

    const dim3 grid((OO / TO) * (BB / TB));  // 64 * 8 = 512 blocks
    const dim3 block(256);
    stimulus_linf_kernel<<<grid, block, 0, stream>>>(x, stim, a, b, state, out);
}

// Round 4
// 74.162 us; speedup vs baseline: 1.1793x; 1.1793x over previous
//
#include <hip/hip_runtime.h>
#include <math.h>

// Problem constants (fixed by the reference).
#define BB 128
#define II 256
#define OO 4096
#define DECAY 0.95f

constexpr int TB  = 16;        // bi rows per block (4 per wave, wave-uniform)
constexpr int TO  = 64;        // o cols per block (one per lane)
constexpr int IC  = 64;        // i-chunk staged in LDS
constexpr int PAD = 4;         // +4 floats row pad -> b128 reads conflict-free
constexpr int LDW = IC + PAD;  // 68
constexpr int NCHUNK = II / IC; // 4

__global__ __launch_bounds__(256) void stimulus_linf_kernel(
    const float* __restrict__ x,     // (B, I)
    const float* __restrict__ stim,  // (O, I)
    const float* __restrict__ a,     // (O,)
    const float* __restrict__ b,     // (O,)
    const float* __restrict__ state, // (B, O)
    float* __restrict__ out)         // (B, O)
{
    // Double-buffered stim tile: 2 x 64 x 68 x 4B = 34.8 KB.
    __shared__ float s_stim[2][TO][LDW];

    const int tid  = threadIdx.x;
    const int lane = tid & 63;
    const int wave = tid >> 6;

    const int o_tile  = blockIdx.x & 63;
    const int bi_tile = blockIdx.x >> 6;
    const int o_base  = o_tile * TO;
    const int bi_base = bi_tile * TB;

    // Wave-uniform x-row base, forced scalar -> SMEM-pipe loads for x.
    const int wrow = __builtin_amdgcn_readfirstlane(bi_base + wave * 4);

    // ---- epilogue prefetch: issue now, consume at the end ----
    const int o   = o_base + lane;
    const float av = a[o];
    const float bv = b[o];
    float st[4];
    #pragma unroll
    for (int r = 0; r < 4; ++r)
        st[r] = state[(bi_base + wave * 4 + r) * OO + o];

    // Scalar (uniform) x-row pointers (full rows; chunk offset added below).
    const float4* xr0 = reinterpret_cast<const float4*>(x + (wrow + 0) * II);
    const float4* xr1 = reinterpret_cast<const float4*>(x + (wrow + 1) * II);
    const float4* xr2 = reinterpret_cast<const float4*>(x + (wrow + 2) * II);
    const float4* xr3 = reinterpret_cast<const float4*>(x + (wrow + 3) * II);

    float d[4] = {0.f, 0.f, 0.f, 0.f};  // |.| >= 0 so 0-init is exact

    // Staging helper: chunk `cc` (i-offset cc*IC) into buffer `buf`.
    // 1024 float4 per chunk, 4 per thread.
    auto stage = [&](int buf, int cc) {
        #pragma unroll
        for (int k = 0; k < 4; ++k) {
            const int idx = tid + k * 256;
            const int row = idx >> 4;   // 16 float4 per row-chunk
            const int c4  = idx & 15;
            const float4 v = *reinterpret_cast<const float4*>(
                &stim[(o_base + row) * II + cc * IC + c4 * 4]);
            *reinterpret_cast<float4*>(&s_stim[buf][row][c4 * 4]) = v;
        }
    };

    stage(0, 0);
    __syncthreads();

    #pragma unroll
    for (int c = 0; c < NCHUNK; ++c) {
        const int cur = c & 1;
        // Prefetch next chunk into the other buffer; these global loads
        // stay in flight across the whole compute phase below.
        if (c < NCHUNK - 1) stage(cur ^ 1, c + 1);

        const int ib = c * (IC / 4);  // float4 offset into x rows
        #pragma unroll 4
        for (int i4 = 0; i4 < IC / 4; ++i4) {
            const float4 s4 =
                *reinterpret_cast<const float4*>(&s_stim[cur][lane][i4 * 4]);
            const float4 xv0 = xr0[ib + i4];
            const float4 xv1 = xr1[ib + i4];
            const float4 xv2 = xr2[ib + i4];
            const float4 xv3 = xr3[ib + i4];
            d[0] = fmaxf(fmaxf(d[0], fabsf(xv0.x - s4.x)), fabsf(xv0.y - s4.y));
            d[0] = fmaxf(fmaxf(d[0], fabsf(xv0.z - s4.z)), fabsf(xv0.w - s4.w));
            d[1] = fmaxf(fmaxf(d[1], fabsf(xv1.x - s4.x)), fabsf(xv1.y - s4.y));
            d[1] = fmaxf(fmaxf(d[1], fabsf(xv1.z - s4.z)), fabsf(xv1.w - s4.w));
            d[2] = fmaxf(fmaxf(d[2], fabsf(xv2.x - s4.x)), fabsf(xv2.y - s4.y));
            d[2] = fmaxf(fmaxf(d[2], fabsf(xv2.z - s4.z)), fabsf(xv2.w - s4.w));
            d[3] = fmaxf(fmaxf(d[3], fabsf(xv3.x - s4.x)), fabsf(xv3.y - s4.y));
            d[3] = fmaxf(fmaxf(d[3], fabsf(xv3.z - s4.z)), fabsf(xv3.w - s4.w));
        }
        // One barrier per chunk: publishes stage(c+1) AND retires all reads
        // of buf `cur` before stage(c+2) overwrites it. Skip after last.
        if (c < NCHUNK - 1) __syncthreads();
    }

    // ---- epilogue: sigmoid((a - d) * b); state*DECAY + value ----
    #pragma unroll
    for (int r = 0; r < 4; ++r) {
        const int bi = bi_base + wave * 4 + r;
        const float z   = (av - d[r]) * bv;
        const float val = 1.f / (1.f + __expf(-z));
        out[bi * OO + o] = st[r] * DECAY + val;
    }
}

extern "C" void kernel_launch(void* const* d_in, const int* in_sizes, int n_in,
                              void* d_out, int out_size, void* d_ws, size_t ws_size,
                              hipStream_t stream) {
    const float* x     = (const float*)d_in[0];
    const float* stim  = (const float*)d_in[1];
    const float* a     = (const float*)d_in[2];
    const float* b     = (const float*)d_in[3];
    const float* state = (const float*)d_in[4];
    float* out = (float*)d_out;

    const dim3 grid((OO / TO) * (BB / TB));  // 64 * 8 = 512 blocks
    const dim3 block(256);
    stimulus_linf_kernel<<<grid, block, 0, stream>>>(x, stim, a, b, state, out);
}

// Round 5
// 73.258 us; speedup vs baseline: 1.1938x; 1.0123x over previous
//
#include <hip/hip_runtime.h>
#include <math.h>

// Problem constants (fixed by the reference).
#define BB 128
#define II 256
#define OO 4096
#define DECAY 0.95f

constexpr int TB  = 16;        // bi rows per block (4 per wave, wave-uniform)
constexpr int TO  = 64;        // o cols per block (one per lane)
constexpr int PAD = 4;         // row pad: lane-stride 260 ≡ 4 mod 32 banks ->
                               // 8 consecutive lanes cover all 32 banks per
                               // b128 phase (conflict-free pattern)
constexpr int LDW = II + PAD;  // 260 floats; row start 1040 B = 16B-aligned

__global__ __launch_bounds__(256) void stimulus_linf_kernel(
    const float* __restrict__ x,     // (B, I)
    const float* __restrict__ stim,  // (O, I)
    const float* __restrict__ a,     // (O,)
    const float* __restrict__ b,     // (O,)
    const float* __restrict__ state, // (B, O)
    float* __restrict__ out)         // (B, O)
{
    // Whole stim tile in LDS: 64 x 260 x 4B = 66.6 KB -> 2 blocks/CU.
    __shared__ float s_stim[TO][LDW];

    const int tid  = threadIdx.x;
    const int lane = tid & 63;
    const int wave = tid >> 6;

    const int o_tile  = blockIdx.x & 63;   // blocks sharing a stim tile sit
    const int bi_tile = blockIdx.x >> 6;   // 64 apart -> same XCD (L2 reuse)
    const int o_base  = o_tile * TO;
    const int bi_base = bi_tile * TB;

    // Wave-uniform x-row base, forced scalar -> SMEM-pipe loads for x.
    const int wrow = __builtin_amdgcn_readfirstlane(bi_base + wave * 4);

    // ---- epilogue prefetch: issue now, consume at the end ----
    const int o   = o_base + lane;
    const float av = a[o];
    const float bv = b[o];
    float st[4];
    #pragma unroll
    for (int r = 0; r < 4; ++r)
        st[r] = state[(bi_base + wave * 4 + r) * OO + o];

    // Scalar (uniform) x-row pointers.
    const float4* xr0 = reinterpret_cast<const float4*>(x + (wrow + 0) * II);
    const float4* xr1 = reinterpret_cast<const float4*>(x + (wrow + 1) * II);
    const float4* xr2 = reinterpret_cast<const float4*>(x + (wrow + 2) * II);
    const float4* xr3 = reinterpret_cast<const float4*>(x + (wrow + 3) * II);

    float d[4] = {0.f, 0.f, 0.f, 0.f};  // |.| >= 0 so 0-init is exact

    // Stage half `h` (cols [h*128, h*128+128)): 2048 float4, 8 per thread,
    // all loads issued back-to-back for max memory-level parallelism.
    auto stage = [&](int h) {
        #pragma unroll
        for (int k = 0; k < 8; ++k) {
            const int idx = tid + k * 256;
            const int row = idx >> 5;          // 32 float4 per half-row
            const int col = h * 128 + (idx & 31) * 4;
            const float4 v = *reinterpret_cast<const float4*>(
                &stim[(o_base + row) * II + col]);
            *reinterpret_cast<float4*>(&s_stim[row][col]) = v;
        }
    };

    auto compute = [&](int i4lo, int i4hi) {
        #pragma unroll 8
        for (int i4 = i4lo; i4 < i4hi; ++i4) {
            const float4 s4 =
                *reinterpret_cast<const float4*>(&s_stim[lane][i4 * 4]);
            const float4 xv0 = xr0[i4];
            const float4 xv1 = xr1[i4];
            const float4 xv2 = xr2[i4];
            const float4 xv3 = xr3[i4];
            d[0] = fmaxf(fmaxf(d[0], fabsf(xv0.x - s4.x)), fabsf(xv0.y - s4.y));
            d[0] = fmaxf(fmaxf(d[0], fabsf(xv0.z - s4.z)), fabsf(xv0.w - s4.w));
            d[1] = fmaxf(fmaxf(d[1], fabsf(xv1.x - s4.x)), fabsf(xv1.y - s4.y));
            d[1] = fmaxf(fmaxf(d[1], fabsf(xv1.z - s4.z)), fabsf(xv1.w - s4.w));
            d[2] = fmaxf(fmaxf(d[2], fabsf(xv2.x - s4.x)), fabsf(xv2.y - s4.y));
            d[2] = fmaxf(fmaxf(d[2], fabsf(xv2.z - s4.z)), fabsf(xv2.w - s4.w));
            d[3] = fmaxf(fmaxf(d[3], fabsf(xv3.x - s4.x)), fabsf(xv3.y - s4.y));
            d[3] = fmaxf(fmaxf(d[3], fabsf(xv3.z - s4.z)), fabsf(xv3.w - s4.w));
        }
    };

    stage(0);
    __syncthreads();          // half 0 visible
    stage(1);                 // half 1 fetch in flight during compute below
    compute(0, 32);
    __syncthreads();          // half 1 visible
    compute(32, 64);          // flat tail, no more syncs

    // ---- epilogue: sigmoid((a - d) * b); state*DECAY + value ----
    #pragma unroll
    for (int r = 0; r < 4; ++r) {
        const int bi = bi_base + wave * 4 + r;
        const float z   = (av - d[r]) * bv;
        const float val = 1.f / (1.f + __expf(-z));
        out[bi * OO + o] = st[r] * DECAY + val;
    }
}

extern "C" void kernel_launch(void* const* d_in, const int* in_sizes, int n_in,
                              void* d_out, int out_size, void* d_ws, size_t ws_size,
                              hipStream_t stream) {
    const float* x     = (const float*)d_in[0];
    const float* stim  = (const float*)d_in[1];
    const float* a     = (const float*)d_in[2];
    const float* b     = (const float*)d_in[3];
    const float* state = (const float*)d_in[4];
    float* out = (float*)d_out;

    const dim3 grid((OO / TO) * (BB / TB));  // 64 * 8 = 512 blocks
    const dim3 block(256);
    stimulus_linf_kernel<<<grid, block, 0, stream>>>(x, stim, a, b, state, out);
}